// Round 8
// baseline (138.306 us; speedup 1.0000x reference)
//
#include <hip/hip_runtime.h>

#define NNODES 50000
#define NEDGES 800000
#define NEDGE4 200000           // NEDGES/4
#define DIMF 128
#define NHEADS 4
#define NEG_SLOPE 0.2f
#define LN_EPS 1e-5f
#define SLOTS 64                // padded bucket; P(deg>=64) negligible
#define NPERX 6250              // nodes per XCD destination range (50000/8)
#define CSRBLK 2048             // scatter blocks (256 per XCD group)

typedef int   v4i __attribute__((ext_vector_type(4)));
typedef float v2f __attribute__((ext_vector_type(2)));

__device__ __forceinline__ unsigned short f2bf(float f) {
    unsigned int u = __float_as_uint(f);
    u = (u + 0x7fffu + ((u >> 16) & 1u)) >> 16;   // RNE
    return (unsigned short)u;
}

// ---------------------------------------------------------------------------
// K1: xw_bf16 = bf16(x @ W) + attention coefficients + cursor zeroing.
// ---------------------------------------------------------------------------
__global__ __launch_bounds__(256) void k_linear(
    const float* __restrict__ x, const float* __restrict__ W,
    const float* __restrict__ att_src, const float* __restrict__ att_dst,
    unsigned short* __restrict__ xwb,
    float* __restrict__ asrc, float* __restrict__ adst,
    int* __restrict__ cursor)
{
    __shared__ float4 Ws4[32 * 32];    // 16 KB (quarter of W: 32 k-rows)
    __shared__ float  xs[64][132];     // 33.8 KB
    const int tid = threadIdx.x;
    const int r8  = tid >> 5;          // 0..7
    const int c32 = tid & 31;          // 0..31
    const int base = blockIdx.x * 64;

    if (tid < 64 && base + tid < NNODES) cursor[base + tid] = 0;

    {
        const float4* x4 = (const float4*)x;
        #pragma unroll
        for (int j = 0; j < 8; ++j) {
            int idx = tid + j * 256;
            int r = idx >> 5, q = idx & 31;
            int gr = base + r;
            float4 v = make_float4(0.f, 0.f, 0.f, 0.f);
            if (gr < NNODES) v = x4[(size_t)gr * 32 + q];
            ((float4*)(&xs[r][0]))[q] = v;
        }
    }

    float accf[8][4];
    #pragma unroll
    for (int i = 0; i < 8; ++i)
        #pragma unroll
        for (int j = 0; j < 4; ++j) accf[i][j] = 0.f;

    const float4* W4 = (const float4*)W;
    for (int qt = 0; qt < 4; ++qt) {
        __syncthreads();
        #pragma unroll
        for (int j = 0; j < 4; ++j)
            Ws4[tid + j * 256] = W4[qt * 1024 + tid + j * 256];
        __syncthreads();
        for (int k4 = 0; k4 < 32; k4 += 4) {
            float xv[8][4];
            #pragma unroll
            for (int i = 0; i < 8; ++i)
                *(float4*)&xv[i][0] = *(const float4*)&xs[i * 8 + r8][qt * 32 + k4];
            #pragma unroll
            for (int kk = 0; kk < 4; ++kk) {
                float4 w4 = Ws4[((k4 + kk) << 5) | c32];
                #pragma unroll
                for (int i = 0; i < 8; ++i) {
                    accf[i][0] += xv[i][kk] * w4.x;
                    accf[i][1] += xv[i][kk] * w4.y;
                    accf[i][2] += xv[i][kk] * w4.z;
                    accf[i][3] += xv[i][kk] * w4.w;
                }
            }
        }
    }

    const int head = c32 >> 3;
    const float* As = att_src + head * 32 + (c32 & 7) * 4;
    const float* Ad = att_dst + head * 32 + (c32 & 7) * 4;
    float a0 = As[0], a1 = As[1], a2 = As[2], a3 = As[3];
    float d0 = Ad[0], d1 = Ad[1], d2 = Ad[2], d3 = Ad[3];
    ushort4* xwb4 = (ushort4*)xwb;

    #pragma unroll
    for (int i = 0; i < 8; ++i) {
        const int row = i * 8 + r8;
        const int grow = base + row;
        float ps = accf[i][0] * a0 + accf[i][1] * a1 + accf[i][2] * a2 + accf[i][3] * a3;
        float pd = accf[i][0] * d0 + accf[i][1] * d1 + accf[i][2] * d2 + accf[i][3] * d3;
        #pragma unroll
        for (int o = 1; o < 8; o <<= 1) {
            ps += __shfl_xor(ps, o);
            pd += __shfl_xor(pd, o);
        }
        if (grow < NNODES) {
            ushort4 u;
            u.x = f2bf(accf[i][0]); u.y = f2bf(accf[i][1]);
            u.z = f2bf(accf[i][2]); u.w = f2bf(accf[i][3]);
            xwb4[(size_t)grow * 32 + c32] = u;
            if ((tid & 7) == 0) {
                asrc[grow * NHEADS + head] = ps;
                adst[grow * NHEADS + head] = pd;
            }
        }
    }
}

// ---------------------------------------------------------------------------
// K2: minimal padded-bucket scatter, XCD-partitioned. Writes ONLY 2 B/edge
// (ushort src). Edge-list reads are NONTEMPORAL so the stream doesn't evict
// the per-XCD 0.8 MB perm window from L2 -> lines fill before evicting.
// ---------------------------------------------------------------------------
__global__ __launch_bounds__(256) void k_scatter(
    const int* __restrict__ esrc, const int* __restrict__ edst,
    int* __restrict__ cursor, unsigned short* __restrict__ perm)
{
    const int lo = (blockIdx.x & 7) * NPERX, hi = lo + NPERX;
    const int stride = (CSRBLK >> 3) * 256;
    const v4i* es4 = (const v4i*)esrc;
    const v4i* ed4 = (const v4i*)edst;
    for (int e = (blockIdx.x >> 3) * 256 + threadIdx.x; e < NEDGE4; e += stride) {
        v4i d4 = __builtin_nontemporal_load(ed4 + e);
        v4i s4 = __builtin_nontemporal_load(es4 + e);
        #pragma unroll
        for (int c = 0; c < 4; ++c) {
            const int dd = d4[c], ss = s4[c];
            if (dd >= lo && dd < hi) {
                int p = atomicAdd(&cursor[dd], 1);
                if (p < SLOTS) perm[(size_t)dd * SLOTS + p] = (unsigned short)ss;
            }
        }
    }
}

// ---------------------------------------------------------------------------
// K_gat: one wave per destination node.
// Phase 0 (batched, parallel): each lane computes its OWN edge's 4 head
//   weights (one L2-resident asrc4 gather + 4 exp), packs them to bf16
//   pairs; denominator = 4 component-wise shfl_xor reductions. No wperm.
// Phase 1: pure gather loop {3 shfl, 1 coalesced 256B gather, 2 FMA},
//   batched 8-deep (8 independent gathers in flight). Fused epilogue.
// ---------------------------------------------------------------------------
__global__ __launch_bounds__(256) void k_gat(
    const float* __restrict__ x, const float* __restrict__ bias,
    const float4* __restrict__ asrc4, const float4* __restrict__ adst4,
    const unsigned int* __restrict__ xwb,
    const int* __restrict__ cursor, const unsigned short* __restrict__ perm,
    const float* __restrict__ ln_g, const float* __restrict__ ln_b,
    const float* __restrict__ prelu_w, float* __restrict__ out)
{
    const int wid  = (blockIdx.x * 256 + threadIdx.x) >> 6;
    const int lane = threadIdx.x & 63;
    if (wid >= NNODES) return;
    const int myh = lane >> 4;        // head owning my 2 output cols

    int cnt = cursor[wid];
    if (cnt > SLOTS) cnt = SLOTS;
    const int sidx = (lane < cnt) ? (int)perm[(size_t)wid * SLOTS + lane] : 0;

    const float4 dvw = adst4[wid];    // uniform
    const float4 avw = asrc4[wid];    // uniform (self)

    // ---- phase 0: per-lane edge weights (4 heads) for edge = slot `lane`
    const float4 ae = asrc4[sidx];    // L2-resident gather (asrc = 0.8 MB)
    float e0 = ae.x + dvw.x, e1 = ae.y + dvw.y;
    float e2 = ae.z + dvw.z, e3 = ae.w + dvw.w;
    e0 = (e0 > 0.f) ? e0 : NEG_SLOPE * e0;
    e1 = (e1 > 0.f) ? e1 : NEG_SLOPE * e1;
    e2 = (e2 > 0.f) ? e2 : NEG_SLOPE * e2;
    e3 = (e3 > 0.f) ? e3 : NEG_SLOPE * e3;
    const bool act = (lane < cnt);
    const float w0 = act ? __expf(e0) : 0.f;
    const float w1 = act ? __expf(e1) : 0.f;
    const float w2 = act ? __expf(e2) : 0.f;
    const float w3 = act ? __expf(e3) : 0.f;
    const unsigned wy = (unsigned)f2bf(w0) | ((unsigned)f2bf(w1) << 16);
    const unsigned wz = (unsigned)f2bf(w2) | ((unsigned)f2bf(w3) << 16);

    // denominator from the SAME bf16-rounded weights
    float r0 = __uint_as_float(wy << 16);
    float r1 = __uint_as_float(wy & 0xffff0000u);
    float r2 = __uint_as_float(wz << 16);
    float r3 = __uint_as_float(wz & 0xffff0000u);
    #pragma unroll
    for (int o = 1; o < 64; o <<= 1) {
        r0 += __shfl_xor(r0, o);
        r1 += __shfl_xor(r1, o);
        r2 += __shfl_xor(r2, o);
        r3 += __shfl_xor(r3, o);
    }

    // self weight (fp32) for my head
    const float av_h = (myh == 0) ? avw.x : (myh == 1) ? avw.y : (myh == 2) ? avw.z : avw.w;
    const float dv_h = (myh == 0) ? dvw.x : (myh == 1) ? dvw.y : (myh == 2) ? dvw.z : dvw.w;
    float lgS = av_h + dv_h;
    lgS = (lgS > 0.f) ? lgS : NEG_SLOPE * lgS;
    const float wself = __expf(lgS);
    const float dsel = (myh == 0) ? r0 : (myh == 1) ? r1 : (myh == 2) ? r2 : r3;
    const float wsum = dsel + wself;

    // accumulator init: self contribution
    const unsigned int vself = xwb[(size_t)wid * 64 + lane];
    float acc0 = wself * __uint_as_float(vself << 16);
    float acc1 = wself * __uint_as_float(vself & 0xffff0000u);

    // ---- phase 1: pure gather loop, 8-deep batches
    for (int j = 0; j * 16 < cnt; ++j) {
        #pragma unroll
        for (int b = 0; b < 2; ++b) {
            const int ebase = j * 16 + b * 8;
            int s_[8]; unsigned wy_[8], wz_[8], v_[8];
            #pragma unroll
            for (int e = 0; e < 8; ++e) {
                s_[e]  = __shfl(sidx, ebase + e);
                wy_[e] = (unsigned)__shfl((int)wy, ebase + e);
                wz_[e] = (unsigned)__shfl((int)wz, ebase + e);
            }
            #pragma unroll
            for (int e = 0; e < 8; ++e)
                v_[e] = xwb[(size_t)s_[e] * 64 + lane];
            #pragma unroll
            for (int e = 0; e < 8; ++e) {
                const unsigned wp = (myh < 2) ? wy_[e] : wz_[e];
                const float w = __uint_as_float((myh & 1) ? (wp & 0xffff0000u)
                                                          : (wp << 16));
                acc0 += w * __uint_as_float(v_[e] << 16);
                acc1 += w * __uint_as_float(v_[e] & 0xffff0000u);
            }
        }
    }

    // epilogue: divide, bias, residual, LN, PReLU
    const float inv = 1.0f / wsum;
    const int c = lane * 2;
    const float2 xr = ((const float2*)x)[(size_t)wid * 64 + lane];
    float h0 = xr.x + acc0 * inv + bias[c];
    float h1 = xr.y + acc1 * inv + bias[c + 1];

    float s1 = h0 + h1, s2 = h0 * h0 + h1 * h1;
    #pragma unroll
    for (int o = 1; o < 64; o <<= 1) {
        s1 += __shfl_xor(s1, o);
        s2 += __shfl_xor(s2, o);
    }
    const float mu  = s1 * (1.f / 128.f);
    const float var = s2 * (1.f / 128.f) - mu * mu;
    const float r   = rsqrtf(var + LN_EPS);

    float g0 = (h0 - mu) * r * ln_g[c]     + ln_b[c];
    float g1 = (h1 - mu) * r * ln_g[c + 1] + ln_b[c + 1];
    const float pw = prelu_w[0];
    g0 = (g0 > 0.f) ? g0 : pw * g0;
    g1 = (g1 > 0.f) ? g1 : pw * g1;

    v2f gv; gv.x = g0; gv.y = g1;
    __builtin_nontemporal_store(gv, (v2f*)out + (size_t)wid * 64 + lane);
}

extern "C" void kernel_launch(void* const* d_in, const int* in_sizes, int n_in,
                              void* d_out, int out_size, void* d_ws, size_t ws_size,
                              hipStream_t stream)
{
    const float* x    = (const float*)d_in[0];
    const int*   eidx = (const int*)  d_in[1];
    const float* W    = (const float*)d_in[2];
    const float* bias = (const float*)d_in[3];
    const float* attS = (const float*)d_in[4];
    const float* attD = (const float*)d_in[5];
    const float* lng  = (const float*)d_in[6];
    const float* lnb  = (const float*)d_in[7];
    const float* pre  = (const float*)d_in[8];

    const int* esrc = eidx;
    const int* edst = eidx + NEDGES;

    // workspace layout (~21 MB)
    unsigned short* xwb = (unsigned short*)d_ws;              // 12.8 MB (bf16 xw)
    float* asrc    = (float*)(xwb + (size_t)NNODES * DIMF);   // 0.8 MB
    float* adst    = asrc + (size_t)NNODES * NHEADS;          // 0.8 MB
    int*   cursor  = (int*)(adst + (size_t)NNODES * NHEADS);  // 0.2 MB
    unsigned short* perm = (unsigned short*)(cursor + NNODES);// 6.4 MB (ushort src)

    k_linear<<<dim3((NNODES + 63) / 64), dim3(256), 0, stream>>>(
        x, W, attS, attD, xwb, asrc, adst, cursor);

    k_scatter<<<dim3(CSRBLK), dim3(256), 0, stream>>>(esrc, edst, cursor, perm);

    k_gat<<<dim3((NNODES * 64 + 255) / 256), dim3(256), 0, stream>>>(
        x, bias, (const float4*)asrc, (const float4*)adst,
        (const unsigned int*)xwb, cursor, perm, lng, lnb, pre, (float*)d_out);
}

// Round 9
// 132.931 us; speedup vs baseline: 1.0404x; 1.0404x over previous
//
#include <hip/hip_runtime.h>

#define NNODES 50000
#define NEDGES 800000
#define NEDGE4 200000           // NEDGES/4
#define DIMF 128
#define NHEADS 4
#define NEG_SLOPE 0.2f
#define LN_EPS 1e-5f
#define SLOTS 64                // padded bucket; P(deg>=64) negligible
#define NPERX 6250              // nodes per XCD destination range (50000/8)
#define CSRBLK 2048             // scatter blocks (256 per XCD group)

typedef int   v4i __attribute__((ext_vector_type(4)));
typedef float v2f __attribute__((ext_vector_type(2)));

__device__ __forceinline__ unsigned short f2bf(float f) {
    unsigned int u = __float_as_uint(f);
    u = (u + 0x7fffu + ((u >> 16) & 1u)) >> 16;   // RNE
    return (unsigned short)u;
}

// ---------------------------------------------------------------------------
// K1: xw_bf16 = bf16(x @ W) + attention coefficients + cursor zeroing.
// ---------------------------------------------------------------------------
__global__ __launch_bounds__(256) void k_linear(
    const float* __restrict__ x, const float* __restrict__ W,
    const float* __restrict__ att_src, const float* __restrict__ att_dst,
    unsigned short* __restrict__ xwb,
    float* __restrict__ asrc, float* __restrict__ adst,
    int* __restrict__ cursor)
{
    __shared__ float4 Ws4[32 * 32];    // 16 KB (quarter of W: 32 k-rows)
    __shared__ float  xs[64][132];     // 33.8 KB
    const int tid = threadIdx.x;
    const int r8  = tid >> 5;          // 0..7
    const int c32 = tid & 31;          // 0..31
    const int base = blockIdx.x * 64;

    if (tid < 64 && base + tid < NNODES) cursor[base + tid] = 0;

    {
        const float4* x4 = (const float4*)x;
        #pragma unroll
        for (int j = 0; j < 8; ++j) {
            int idx = tid + j * 256;
            int r = idx >> 5, q = idx & 31;
            int gr = base + r;
            float4 v = make_float4(0.f, 0.f, 0.f, 0.f);
            if (gr < NNODES) v = x4[(size_t)gr * 32 + q];
            ((float4*)(&xs[r][0]))[q] = v;
        }
    }

    float accf[8][4];
    #pragma unroll
    for (int i = 0; i < 8; ++i)
        #pragma unroll
        for (int j = 0; j < 4; ++j) accf[i][j] = 0.f;

    const float4* W4 = (const float4*)W;
    for (int qt = 0; qt < 4; ++qt) {
        __syncthreads();
        #pragma unroll
        for (int j = 0; j < 4; ++j)
            Ws4[tid + j * 256] = W4[qt * 1024 + tid + j * 256];
        __syncthreads();
        for (int k4 = 0; k4 < 32; k4 += 4) {
            float xv[8][4];
            #pragma unroll
            for (int i = 0; i < 8; ++i)
                *(float4*)&xv[i][0] = *(const float4*)&xs[i * 8 + r8][qt * 32 + k4];
            #pragma unroll
            for (int kk = 0; kk < 4; ++kk) {
                float4 w4 = Ws4[((k4 + kk) << 5) | c32];
                #pragma unroll
                for (int i = 0; i < 8; ++i) {
                    accf[i][0] += xv[i][kk] * w4.x;
                    accf[i][1] += xv[i][kk] * w4.y;
                    accf[i][2] += xv[i][kk] * w4.z;
                    accf[i][3] += xv[i][kk] * w4.w;
                }
            }
        }
    }

    const int head = c32 >> 3;
    const float* As = att_src + head * 32 + (c32 & 7) * 4;
    const float* Ad = att_dst + head * 32 + (c32 & 7) * 4;
    float a0 = As[0], a1 = As[1], a2 = As[2], a3 = As[3];
    float d0 = Ad[0], d1 = Ad[1], d2 = Ad[2], d3 = Ad[3];
    ushort4* xwb4 = (ushort4*)xwb;

    #pragma unroll
    for (int i = 0; i < 8; ++i) {
        const int row = i * 8 + r8;
        const int grow = base + row;
        float ps = accf[i][0] * a0 + accf[i][1] * a1 + accf[i][2] * a2 + accf[i][3] * a3;
        float pd = accf[i][0] * d0 + accf[i][1] * d1 + accf[i][2] * d2 + accf[i][3] * d3;
        #pragma unroll
        for (int o = 1; o < 8; o <<= 1) {
            ps += __shfl_xor(ps, o);
            pd += __shfl_xor(pd, o);
        }
        if (grow < NNODES) {
            ushort4 u;
            u.x = f2bf(accf[i][0]); u.y = f2bf(accf[i][1]);
            u.z = f2bf(accf[i][2]); u.w = f2bf(accf[i][3]);
            xwb4[(size_t)grow * 32 + c32] = u;
            if ((tid & 7) == 0) {
                asrc[grow * NHEADS + head] = ps;
                adst[grow * NHEADS + head] = pd;
            }
        }
    }
}

// ---------------------------------------------------------------------------
// K2: minimal padded-bucket scatter, XCD-partitioned. Writes ONLY 2 B/edge.
// ---------------------------------------------------------------------------
__global__ __launch_bounds__(256) void k_scatter(
    const int* __restrict__ esrc, const int* __restrict__ edst,
    int* __restrict__ cursor, unsigned short* __restrict__ perm)
{
    const int lo = (blockIdx.x & 7) * NPERX, hi = lo + NPERX;
    const int stride = (CSRBLK >> 3) * 256;
    const v4i* es4 = (const v4i*)esrc;
    const v4i* ed4 = (const v4i*)edst;
    for (int e = (blockIdx.x >> 3) * 256 + threadIdx.x; e < NEDGE4; e += stride) {
        v4i d4 = __builtin_nontemporal_load(ed4 + e);
        v4i s4 = __builtin_nontemporal_load(es4 + e);
        #pragma unroll
        for (int c = 0; c < 4; ++c) {
            const int dd = d4[c], ss = s4[c];
            if (dd >= lo && dd < hi) {
                int p = atomicAdd(&cursor[dd], 1);
                if (p < SLOTS) perm[(size_t)dd * SLOTS + p] = (unsigned short)ss;
            }
        }
    }
}

// ---------------------------------------------------------------------------
// K3: per-edge weights, fully coalesced I/O. One wave per node: read the
// node's 64 perm slots (128 B/wave), gather asrc4[s] (0.8 MB, L2-resident),
// 4x leaky+exp, pack bf16x4, write wperm[wid*64+lane] contiguous (512 B/wave
// full lines). Empty slots -> 0, so k_gat needs no masking at all.
// ---------------------------------------------------------------------------
__global__ __launch_bounds__(256) void k_weights(
    const float4* __restrict__ asrc4, const float4* __restrict__ adst4,
    const int* __restrict__ cursor, const unsigned short* __restrict__ perm,
    ushort4* __restrict__ wperm)
{
    const int wid  = (blockIdx.x * 256 + threadIdx.x) >> 6;
    const int lane = threadIdx.x & 63;
    if (wid >= NNODES) return;

    int cnt = cursor[wid];
    if (cnt > SLOTS) cnt = SLOTS;
    const float4 dv = adst4[wid];

    ushort4 wu = make_ushort4(0, 0, 0, 0);
    if (lane < cnt) {
        const int s = (int)perm[(size_t)wid * SLOTS + lane];
        const float4 ae = asrc4[s];
        float l0 = ae.x + dv.x, l1 = ae.y + dv.y;
        float l2 = ae.z + dv.z, l3 = ae.w + dv.w;
        l0 = (l0 > 0.f) ? l0 : NEG_SLOPE * l0;
        l1 = (l1 > 0.f) ? l1 : NEG_SLOPE * l1;
        l2 = (l2 > 0.f) ? l2 : NEG_SLOPE * l2;
        l3 = (l3 > 0.f) ? l3 : NEG_SLOPE * l3;
        wu.x = f2bf(__expf(l0)); wu.y = f2bf(__expf(l1));
        wu.z = f2bf(__expf(l2)); wu.w = f2bf(__expf(l3));
    }
    wperm[(size_t)wid * SLOTS + lane] = wu;
}

// ---------------------------------------------------------------------------
// K_gat (R7-proven structure): one wave per destination node. Weights are
// streamed coalesced from wperm (zero-padded -> no masks); inner loop is
// pure {shfl, coalesced 256B gather, 2 FMA} batched 8-deep. Denominator
// from the weight stream via 4 shfl_xor. Fused epilogue -> d_out once.
// ---------------------------------------------------------------------------
__global__ __launch_bounds__(256) void k_gat(
    const float* __restrict__ x, const float* __restrict__ bias,
    const float* __restrict__ asrc, const float* __restrict__ adst,
    const unsigned int* __restrict__ xwb,
    const int* __restrict__ cursor, const unsigned short* __restrict__ perm,
    const unsigned short* __restrict__ wperm_u16,
    const float* __restrict__ ln_g, const float* __restrict__ ln_b,
    const float* __restrict__ prelu_w, float* __restrict__ out)
{
    const int wid  = (blockIdx.x * 256 + threadIdx.x) >> 6;
    const int lane = threadIdx.x & 63;
    if (wid >= NNODES) return;
    const int myh = lane >> 4;        // head owning my 2 output cols
    const int hb  = lane & 3;         // head in the weight stream

    // self-loop weight (fp32, per-lane for head hb)
    const float adh_b = adst[wid * NHEADS + hb];
    float lgS = asrc[wid * NHEADS + hb] + adh_b;
    lgS = (lgS > 0.f) ? lgS : NEG_SLOPE * lgS;
    const float wself_b = __expf(lgS);

    int cnt = cursor[wid];
    if (cnt > SLOTS) cnt = SLOTS;
    const int sidx = (lane < cnt) ? (int)perm[(size_t)wid * SLOTS + lane] : 0;

    const float wself = __shfl(wself_b, myh);
    const unsigned int vself = xwb[(size_t)wid * 64 + lane];
    float acc0 = wself * __uint_as_float(vself << 16);
    float acc1 = wself * __uint_as_float(vself & 0xffff0000u);
    float dsum = 0.f;

    const int jmax = (cnt + 15) >> 4;
    for (int j = 0; j < jmax; ++j) {
        // weight stream: lane holds edge (j*16 + (lane>>2)), head (lane&3);
        // zero-padded slots make masking unnecessary.
        const unsigned short wu = wperm_u16[(size_t)wid * 256 + j * 64 + lane];
        const float wv = __uint_as_float(((unsigned)wu) << 16);
        dsum += wv;

        #pragma unroll
        for (int b = 0; b < 2; ++b) {
            const int ebase = j * 16 + b * 8;
            int s_[8]; float w_[8]; unsigned v_[8];
            #pragma unroll
            for (int e = 0; e < 8; ++e) {
                s_[e] = __shfl(sidx, ebase + e);
                w_[e] = __shfl(wv, ((b * 8 + e) << 2) | myh);
            }
            #pragma unroll
            for (int e = 0; e < 8; ++e)
                v_[e] = xwb[(size_t)s_[e] * 64 + lane];
            #pragma unroll
            for (int e = 0; e < 8; ++e) {
                acc0 += w_[e] * __uint_as_float(v_[e] << 16);
                acc1 += w_[e] * __uint_as_float(v_[e] & 0xffff0000u);
            }
        }
    }

    // denominator: sum over the 16 lanes sharing head hb, add self, remap
    #pragma unroll
    for (int o = 4; o < 64; o <<= 1) dsum += __shfl_xor(dsum, o);
    const float wsum = __shfl(dsum + wself_b, myh);

    // epilogue: divide, bias, residual, LN, PReLU
    const float inv = 1.0f / wsum;
    const int c = lane * 2;
    const float2 xr = ((const float2*)x)[(size_t)wid * 64 + lane];
    float h0 = xr.x + acc0 * inv + bias[c];
    float h1 = xr.y + acc1 * inv + bias[c + 1];

    float s1 = h0 + h1, s2 = h0 * h0 + h1 * h1;
    #pragma unroll
    for (int o = 1; o < 64; o <<= 1) {
        s1 += __shfl_xor(s1, o);
        s2 += __shfl_xor(s2, o);
    }
    const float mu  = s1 * (1.f / 128.f);
    const float var = s2 * (1.f / 128.f) - mu * mu;
    const float r   = rsqrtf(var + LN_EPS);

    float g0 = (h0 - mu) * r * ln_g[c]     + ln_b[c];
    float g1 = (h1 - mu) * r * ln_g[c + 1] + ln_b[c + 1];
    const float pw = prelu_w[0];
    g0 = (g0 > 0.f) ? g0 : pw * g0;
    g1 = (g1 > 0.f) ? g1 : pw * g1;

    v2f gv; gv.x = g0; gv.y = g1;
    __builtin_nontemporal_store(gv, (v2f*)out + (size_t)wid * 64 + lane);
}

extern "C" void kernel_launch(void* const* d_in, const int* in_sizes, int n_in,
                              void* d_out, int out_size, void* d_ws, size_t ws_size,
                              hipStream_t stream)
{
    const float* x    = (const float*)d_in[0];
    const int*   eidx = (const int*)  d_in[1];
    const float* W    = (const float*)d_in[2];
    const float* bias = (const float*)d_in[3];
    const float* attS = (const float*)d_in[4];
    const float* attD = (const float*)d_in[5];
    const float* lng  = (const float*)d_in[6];
    const float* lnb  = (const float*)d_in[7];
    const float* pre  = (const float*)d_in[8];

    const int* esrc = eidx;
    const int* edst = eidx + NEDGES;

    // workspace layout (~47 MB)
    unsigned short* xwb = (unsigned short*)d_ws;              // 12.8 MB (bf16 xw)
    float* asrc    = (float*)(xwb + (size_t)NNODES * DIMF);   // 0.8 MB
    float* adst    = asrc + (size_t)NNODES * NHEADS;          // 0.8 MB
    int*   cursor  = (int*)(adst + (size_t)NNODES * NHEADS);  // 0.2 MB
    unsigned short* perm = (unsigned short*)(cursor + NNODES);// 6.4 MB (ushort src)
    ushort4* wperm = (ushort4*)(perm + (size_t)NNODES * SLOTS); // 25.6 MB (bf16x4)

    k_linear<<<dim3((NNODES + 63) / 64), dim3(256), 0, stream>>>(
        x, W, attS, attD, xwb, asrc, adst, cursor);

    k_scatter<<<dim3(CSRBLK), dim3(256), 0, stream>>>(esrc, edst, cursor, perm);

    k_weights<<<dim3((NNODES * 64 + 255) / 256), dim3(256), 0, stream>>>(
        (const float4*)asrc, (const float4*)adst, cursor, perm, wperm);

    k_gat<<<dim3((NNODES * 64 + 255) / 256), dim3(256), 0, stream>>>(
        x, bias, asrc, adst, (const unsigned int*)xwb, cursor, perm,
        (const unsigned short*)wperm, lng, lnb, pre, (float*)d_out);
}

// Round 10
// 122.995 us; speedup vs baseline: 1.1245x; 1.0808x over previous
//
#include <hip/hip_runtime.h>

#define NNODES 50000
#define NEDGES 800000
#define NEDGE4 200000           // NEDGES/4
#define DIMF 128
#define NHEADS 4
#define NEG_SLOPE 0.2f
#define LN_EPS 1e-5f
#define SLOTS 64                // padded bucket; P(deg>=64) negligible
#define NPERX 6250              // nodes per XCD destination range (50000/8)
#define CSRBLK 2048             // scatter blocks (256 per XCD group)

typedef int   v4i   __attribute__((ext_vector_type(4)));
typedef float v2f   __attribute__((ext_vector_type(2)));
typedef short bf16x8 __attribute__((ext_vector_type(8)));
typedef float f32x4  __attribute__((ext_vector_type(4)));

__device__ __forceinline__ unsigned short f2bf(float f) {
    unsigned int u = __float_as_uint(f);
    u = (u + 0x7fffu + ((u >> 16) & 1u)) >> 16;   // RNE
    return (unsigned short)u;
}

// ---------------------------------------------------------------------------
// K1 (MFMA): xw_bf16 = bf16(x @ W) via v_mfma_f32_16x16x32_bf16.
// W^T staged once in LDS as bf16 [128][136] (pad 8 -> 272 B rows, 16B-aligned
// b128 reads, ~2-way bank alias only). Per block: 64 rows, 4 waves; per wave
// 16 rows x 128 cols = 8 C-tiles, 32 MFMAs. A-frag: row=lane&15,
// k=(lane>>4)*8+j (8 contiguous fp32 -> bf16). B-frag: col=lane&15, same k
// (contiguous in W^T). C: col=lane&15, row=(lane>>4)*4+r [m89-verified].
// Attention dots from fp32 C-frags, 16-lane shfl_xor reduce, float4 stores.
// ---------------------------------------------------------------------------
__global__ __launch_bounds__(256) void k_linear(
    const float* __restrict__ x, const float* __restrict__ W,
    const float* __restrict__ att_src, const float* __restrict__ att_dst,
    unsigned short* __restrict__ xwb,
    float* __restrict__ asrc, float* __restrict__ adst,
    int* __restrict__ cursor)
{
    __shared__ unsigned short Wt[128][136];   // 34.8 KB, bf16 W^T
    const int tid  = threadIdx.x;
    const int base = blockIdx.x * 64;

    if (tid < 64 && base + tid < NNODES) cursor[base + tid] = 0;

    // stage Wt = bf16(W^T): thread (k=tid>>5 step 8, nq=tid&31)
    {
        const float4* W4 = (const float4*)W;
        const int nq = tid & 31;
        int k = tid >> 5;
        #pragma unroll
        for (int it = 0; it < 16; ++it, k += 8) {
            float4 wv = W4[k * 32 + nq];
            Wt[nq * 4 + 0][k] = f2bf(wv.x);
            Wt[nq * 4 + 1][k] = f2bf(wv.y);
            Wt[nq * 4 + 2][k] = f2bf(wv.z);
            Wt[nq * 4 + 3][k] = f2bf(wv.w);
        }
    }
    __syncthreads();

    const int wv_   = tid >> 6;        // wave 0..3
    const int lane  = tid & 63;
    const int row16 = lane & 15;
    const int kg    = lane >> 4;       // 0..3
    const int grow_a = base + wv_ * 16 + row16;
    const int arow   = (grow_a < NNODES) ? grow_a : 0;   // clamp OOB reads

    f32x4 acc[8];
    #pragma unroll
    for (int ct = 0; ct < 8; ++ct) acc[ct] = (f32x4){0.f, 0.f, 0.f, 0.f};

    #pragma unroll
    for (int ks = 0; ks < 4; ++ks) {
        // A-frag: x[arow][ks*32 + kg*8 .. +8)
        const float4* xr = (const float4*)(x + (size_t)arow * DIMF + ks * 32 + kg * 8);
        const float4 xa = xr[0], xb = xr[1];
        bf16x8 af;
        af[0] = (short)f2bf(xa.x); af[1] = (short)f2bf(xa.y);
        af[2] = (short)f2bf(xa.z); af[3] = (short)f2bf(xa.w);
        af[4] = (short)f2bf(xb.x); af[5] = (short)f2bf(xb.y);
        af[6] = (short)f2bf(xb.z); af[7] = (short)f2bf(xb.w);
        #pragma unroll
        for (int ct = 0; ct < 8; ++ct) {
            const bf16x8 bfr = *(const bf16x8*)&Wt[ct * 16 + row16][ks * 32 + kg * 8];
            acc[ct] = __builtin_amdgcn_mfma_f32_16x16x32_bf16(af, bfr, acc[ct], 0, 0, 0);
        }
    }

    // xwb store: C layout col=lane&15, row=(lane>>4)*4+r
    #pragma unroll
    for (int ct = 0; ct < 8; ++ct) {
        const int col = ct * 16 + row16;
        #pragma unroll
        for (int r = 0; r < 4; ++r) {
            const int grow = base + wv_ * 16 + kg * 4 + r;
            if (grow < NNODES)
                xwb[(size_t)grow * DIMF + col] = f2bf(acc[ct][r]);
        }
    }

    // attention dots: ps[h][r] = <xw[row, h*32:(h+1)*32], att_src[h]>
    float ps[4][4], pd[4][4];
    #pragma unroll
    for (int h = 0; h < 4; ++h)
        #pragma unroll
        for (int r = 0; r < 4; ++r) { ps[h][r] = 0.f; pd[h][r] = 0.f; }
    #pragma unroll
    for (int ct = 0; ct < 8; ++ct) {
        const int h    = ct >> 1;
        const int cmod = (ct & 1) * 16 + row16;
        const float aS = att_src[h * 32 + cmod];
        const float aD = att_dst[h * 32 + cmod];
        #pragma unroll
        for (int r = 0; r < 4; ++r) {
            ps[h][r] += acc[ct][r] * aS;
            pd[h][r] += acc[ct][r] * aD;
        }
    }
    #pragma unroll
    for (int o = 1; o < 16; o <<= 1) {
        #pragma unroll
        for (int h = 0; h < 4; ++h)
            #pragma unroll
            for (int r = 0; r < 4; ++r) {
                ps[h][r] += __shfl_xor(ps[h][r], o);
                pd[h][r] += __shfl_xor(pd[h][r], o);
            }
    }
    if (row16 == 0) {
        #pragma unroll
        for (int r = 0; r < 4; ++r) {
            const int grow = base + wv_ * 16 + kg * 4 + r;
            if (grow < NNODES) {
                ((float4*)asrc)[grow] = make_float4(ps[0][r], ps[1][r], ps[2][r], ps[3][r]);
                ((float4*)adst)[grow] = make_float4(pd[0][r], pd[1][r], pd[2][r], pd[3][r]);
            }
        }
    }
}

// ---------------------------------------------------------------------------
// K2: minimal padded-bucket scatter, XCD-partitioned. Writes ONLY 2 B/edge.
// ---------------------------------------------------------------------------
__global__ __launch_bounds__(256) void k_scatter(
    const int* __restrict__ esrc, const int* __restrict__ edst,
    int* __restrict__ cursor, unsigned short* __restrict__ perm)
{
    const int lo = (blockIdx.x & 7) * NPERX, hi = lo + NPERX;
    const int stride = (CSRBLK >> 3) * 256;
    const v4i* es4 = (const v4i*)esrc;
    const v4i* ed4 = (const v4i*)edst;
    for (int e = (blockIdx.x >> 3) * 256 + threadIdx.x; e < NEDGE4; e += stride) {
        v4i d4 = __builtin_nontemporal_load(ed4 + e);
        v4i s4 = __builtin_nontemporal_load(es4 + e);
        #pragma unroll
        for (int c = 0; c < 4; ++c) {
            const int dd = d4[c], ss = s4[c];
            if (dd >= lo && dd < hi) {
                int p = atomicAdd(&cursor[dd], 1);
                if (p < SLOTS) perm[(size_t)dd * SLOTS + p] = (unsigned short)ss;
            }
        }
    }
}

// ---------------------------------------------------------------------------
// K3: per-edge weights, fully coalesced I/O. One wave per node.
// ---------------------------------------------------------------------------
__global__ __launch_bounds__(256) void k_weights(
    const float4* __restrict__ asrc4, const float4* __restrict__ adst4,
    const int* __restrict__ cursor, const unsigned short* __restrict__ perm,
    ushort4* __restrict__ wperm)
{
    const int wid  = (blockIdx.x * 256 + threadIdx.x) >> 6;
    const int lane = threadIdx.x & 63;
    if (wid >= NNODES) return;

    int cnt = cursor[wid];
    if (cnt > SLOTS) cnt = SLOTS;
    const float4 dv = adst4[wid];

    ushort4 wu = make_ushort4(0, 0, 0, 0);
    if (lane < cnt) {
        const int s = (int)perm[(size_t)wid * SLOTS + lane];
        const float4 ae = asrc4[s];
        float l0 = ae.x + dv.x, l1 = ae.y + dv.y;
        float l2 = ae.z + dv.z, l3 = ae.w + dv.w;
        l0 = (l0 > 0.f) ? l0 : NEG_SLOPE * l0;
        l1 = (l1 > 0.f) ? l1 : NEG_SLOPE * l1;
        l2 = (l2 > 0.f) ? l2 : NEG_SLOPE * l2;
        l3 = (l3 > 0.f) ? l3 : NEG_SLOPE * l3;
        wu.x = f2bf(__expf(l0)); wu.y = f2bf(__expf(l1));
        wu.z = f2bf(__expf(l2)); wu.w = f2bf(__expf(l3));
    }
    wperm[(size_t)wid * SLOTS + lane] = wu;
}

// ---------------------------------------------------------------------------
// K_gat (R7-proven structure): one wave per destination node. Weights are
// streamed coalesced from wperm (zero-padded -> no masks); inner loop is
// pure {shfl, coalesced 256B gather, 2 FMA} batched 8-deep. Denominator
// from the weight stream via 4 shfl_xor. Fused epilogue -> d_out once.
// ---------------------------------------------------------------------------
__global__ __launch_bounds__(256) void k_gat(
    const float* __restrict__ x, const float* __restrict__ bias,
    const float* __restrict__ asrc, const float* __restrict__ adst,
    const unsigned int* __restrict__ xwb,
    const int* __restrict__ cursor, const unsigned short* __restrict__ perm,
    const unsigned short* __restrict__ wperm_u16,
    const float* __restrict__ ln_g, const float* __restrict__ ln_b,
    const float* __restrict__ prelu_w, float* __restrict__ out)
{
    const int wid  = (blockIdx.x * 256 + threadIdx.x) >> 6;
    const int lane = threadIdx.x & 63;
    if (wid >= NNODES) return;
    const int myh = lane >> 4;        // head owning my 2 output cols
    const int hb  = lane & 3;         // head in the weight stream

    // self-loop weight (fp32, per-lane for head hb)
    const float adh_b = adst[wid * NHEADS + hb];
    float lgS = asrc[wid * NHEADS + hb] + adh_b;
    lgS = (lgS > 0.f) ? lgS : NEG_SLOPE * lgS;
    const float wself_b = __expf(lgS);

    int cnt = cursor[wid];
    if (cnt > SLOTS) cnt = SLOTS;
    const int sidx = (lane < cnt) ? (int)perm[(size_t)wid * SLOTS + lane] : 0;

    const float wself = __shfl(wself_b, myh);
    const unsigned int vself = xwb[(size_t)wid * 64 + lane];
    float acc0 = wself * __uint_as_float(vself << 16);
    float acc1 = wself * __uint_as_float(vself & 0xffff0000u);
    float dsum = 0.f;

    const int jmax = (cnt + 15) >> 4;
    for (int j = 0; j < jmax; ++j) {
        // weight stream: lane holds edge (j*16 + (lane>>2)), head (lane&3);
        // zero-padded slots make masking unnecessary.
        const unsigned short wu = wperm_u16[(size_t)wid * 256 + j * 64 + lane];
        const float wv = __uint_as_float(((unsigned)wu) << 16);
        dsum += wv;

        #pragma unroll
        for (int b = 0; b < 2; ++b) {
            const int ebase = j * 16 + b * 8;
            int s_[8]; float w_[8]; unsigned v_[8];
            #pragma unroll
            for (int e = 0; e < 8; ++e) {
                s_[e] = __shfl(sidx, ebase + e);
                w_[e] = __shfl(wv, ((b * 8 + e) << 2) | myh);
            }
            #pragma unroll
            for (int e = 0; e < 8; ++e)
                v_[e] = xwb[(size_t)s_[e] * 64 + lane];
            #pragma unroll
            for (int e = 0; e < 8; ++e) {
                acc0 += w_[e] * __uint_as_float(v_[e] << 16);
                acc1 += w_[e] * __uint_as_float(v_[e] & 0xffff0000u);
            }
        }
    }

    // denominator: sum over the 16 lanes sharing head hb, add self, remap
    #pragma unroll
    for (int o = 4; o < 64; o <<= 1) dsum += __shfl_xor(dsum, o);
    const float wsum = __shfl(dsum + wself_b, myh);

    // epilogue: divide, bias, residual, LN, PReLU
    const float inv = 1.0f / wsum;
    const int c = lane * 2;
    const float2 xr = ((const float2*)x)[(size_t)wid * 64 + lane];
    float h0 = xr.x + acc0 * inv + bias[c];
    float h1 = xr.y + acc1 * inv + bias[c + 1];

    float s1 = h0 + h1, s2 = h0 * h0 + h1 * h1;
    #pragma unroll
    for (int o = 1; o < 64; o <<= 1) {
        s1 += __shfl_xor(s1, o);
        s2 += __shfl_xor(s2, o);
    }
    const float mu  = s1 * (1.f / 128.f);
    const float var = s2 * (1.f / 128.f) - mu * mu;
    const float r   = rsqrtf(var + LN_EPS);

    float g0 = (h0 - mu) * r * ln_g[c]     + ln_b[c];
    float g1 = (h1 - mu) * r * ln_g[c + 1] + ln_b[c + 1];
    const float pw = prelu_w[0];
    g0 = (g0 > 0.f) ? g0 : pw * g0;
    g1 = (g1 > 0.f) ? g1 : pw * g1;

    v2f gv; gv.x = g0; gv.y = g1;
    __builtin_nontemporal_store(gv, (v2f*)out + (size_t)wid * 64 + lane);
}

extern "C" void kernel_launch(void* const* d_in, const int* in_sizes, int n_in,
                              void* d_out, int out_size, void* d_ws, size_t ws_size,
                              hipStream_t stream)
{
    const float* x    = (const float*)d_in[0];
    const int*   eidx = (const int*)  d_in[1];
    const float* W    = (const float*)d_in[2];
    const float* bias = (const float*)d_in[3];
    const float* attS = (const float*)d_in[4];
    const float* attD = (const float*)d_in[5];
    const float* lng  = (const float*)d_in[6];
    const float* lnb  = (const float*)d_in[7];
    const float* pre  = (const float*)d_in[8];

    const int* esrc = eidx;
    const int* edst = eidx + NEDGES;

    // workspace layout (~47 MB)
    unsigned short* xwb = (unsigned short*)d_ws;              // 12.8 MB (bf16 xw)
    float* asrc    = (float*)(xwb + (size_t)NNODES * DIMF);   // 0.8 MB
    float* adst    = asrc + (size_t)NNODES * NHEADS;          // 0.8 MB
    int*   cursor  = (int*)(adst + (size_t)NNODES * NHEADS);  // 0.2 MB
    unsigned short* perm = (unsigned short*)(cursor + NNODES);// 6.4 MB (ushort src)
    ushort4* wperm = (ushort4*)(perm + (size_t)NNODES * SLOTS); // 25.6 MB (bf16x4)

    k_linear<<<dim3((NNODES + 63) / 64), dim3(256), 0, stream>>>(
        x, W, attS, attD, xwb, asrc, adst, cursor);

    k_scatter<<<dim3(CSRBLK), dim3(256), 0, stream>>>(esrc, edst, cursor, perm);

    k_weights<<<dim3((NNODES * 64 + 255) / 256), dim3(256), 0, stream>>>(
        (const float4*)asrc, (const float4*)adst, cursor, perm, wperm);

    k_gat<<<dim3((NNODES * 64 + 255) / 256), dim3(256), 0, stream>>>(
        x, bias, asrc, adst, (const unsigned int*)xwb, cursor, perm,
        (const unsigned short*)wperm, lng, lnb, pre, (float*)d_out);
}